// Round 4
// baseline (337.208 us; speedup 1.0000x reference)
//
#include <hip/hip_runtime.h>
#include <hip/hip_bf16.h>

#define M_DIM 64
#define K_DIM 4096
#define N_DIM 14336
#define NBLKS 224       // one block per 64 n-cols
#define WCHUNKS 16      // 32-k chunks per wave (interleaved: g = wv + 8*cc)

typedef __attribute__((ext_vector_type(8))) short bf16x8;
typedef __attribute__((ext_vector_type(4))) float f32x4;
typedef __attribute__((ext_vector_type(4))) int i32x4;
typedef unsigned short u16;

// ---------------------------------------------------------------------------
// prep v3: pure split of x (fp32) into bf16 hi/lo in MFMA-A-fragment layout
// (elem idx = (k/8)*(64*8) + m*8 + (k%8)). 256 blocks x 128 threads, pure
// streaming. rowsum computed in wqmm via ones-B MFMA.
__global__ __launch_bounds__(128) void prep_split(
    const float* __restrict__ x, u16* __restrict__ xh, u16* __restrict__ xl) {
  int tg = blockIdx.x * 128 + threadIdx.x;  // 0..32767
  int kb = tg & 511;
  int m = tg >> 9;
  const float* xp = x + m * K_DIM + kb * 8;
  u16 hs[8], ls[8];
#pragma unroll
  for (int j = 0; j < 8; ++j) {
    float v = xp[j];
    unsigned hv = __float_as_uint(v) & 0xFFFF0000u;  // bf16 truncate (exact)
    float r = v - __uint_as_float(hv);
    hs[j] = (u16)(hv >> 16);
    ls[j] = (u16)(__float_as_uint(r) >> 16);
  }
  int o = kb * (M_DIM * 8) + m * 8;
  *(uint4*)(xh + o) = *(uint4*)hs;
  *(uint4*)(xl + o) = *(uint4*)ls;
}

// ---------------------------------------------------------------------------
// Streaming GEMM v8b — v8 with the A-buffer clobber fixed (R3 post-mortem:
// LOADA(c+2,0) was issued before MMA(0) consumed abh[0]/abl[0]).
//  * dwordx4 W loads: 8 VMEM/chunk (was 32), 16 B/lane. Frag col = 4*lnk+f;
//    LDS deposit keeps conflict-free f*16+lnk index; epilogue un-permutes
//    (n = nbase + 4*(nc&15) + (nc>>4)).
//  * LOADW(c+2) issues right after PACK(c) frees rw[0], BEFORE the MFMAs;
//    LOADA(c+2) issues AFTER MMA(0) (A is L2-hot, latency hidden by the
//    next PACK+MMA half-iteration).
//  * interleaved k-front: wave wv takes global chunks wv, wv+8, ... so the
//    device sweeps one contiguous 256-row band (DRAM page locality).
__global__ __launch_bounds__(512, 2) void wqmm(
    const int* __restrict__ W, const u16* __restrict__ xh,
    const u16* __restrict__ xl, const float* __restrict__ scale,
    const float* __restrict__ offset, const float* __restrict__ bias,
    float* __restrict__ out) {
  __shared__ __align__(16) float red[4][64][66];  // 67.6 KB; col 64 = rowsum

  const int t = threadIdx.x;
  const int lane = t & 63;
  const int wv = t >> 6;       // 0..7
  const int quad = lane >> 4;
  const int lnk = lane & 15;
  const int nbase = blockIdx.x * 64;

  // W: per-lane dword offset within a k-row (x4 load: cols 4*lnk..4*lnk+3)
  const int wcol = nbase + 4 * lnk;
  // A: base for (k/8) group = (wv + 8*cc)*4 + quad, m = mt*16 + lnk
  const u16* xhp = xh + (size_t)(wv * 4 + quad) * 512 + lnk * 8;
  const u16* xlp = xl + (size_t)(wv * 4 + quad) * 512 + lnk * 8;

  // constant ones B-fragment (bf16 1.0 = 0x3F80) for the rowsum MFMA
  const bf16x8 bones = {(short)0x3F80, (short)0x3F80, (short)0x3F80,
                        (short)0x3F80, (short)0x3F80, (short)0x3F80,
                        (short)0x3F80, (short)0x3F80};

  f32x4 acc[4][4] = {};       // [m-tile][n-frag]
  f32x4 acc1[4] = {};         // [m-tile] rowsum accumulator
  __align__(16) int rw[2][8][4];  // W dbuf: [buf][k-row j][x4 comp f]
  bf16x8 abh[2][4], abl[2][4];  // A double buffer
  bf16x8 bfr[4];              // packed B frags (live PACK -> MMA)

  // global chunk index g = wv + 8*CC; k-rows = g*32 + quad*8 + j
#define LOADW(CC, BUF)                                                     \
  do {                                                                     \
    const int* bp =                                                        \
        W + (size_t)((wv + 8 * (CC)) * 32 + quad * 8) * N_DIM + wcol;      \
    _Pragma("unroll") for (int j = 0; j < 8; ++j)                          \
        *(i32x4*)rw[BUF][j] = *(const i32x4*)(bp + (size_t)j * N_DIM);     \
  } while (0)

#define LOADA(CC, BUF)                                            \
  do {                                                            \
    const u16* ahc = xhp + (size_t)(CC) * 16384;                  \
    const u16* alc = xlp + (size_t)(CC) * 16384;                  \
    _Pragma("unroll") for (int mt = 0; mt < 4; ++mt) {            \
      abh[BUF][mt] = *(const bf16x8*)(ahc + mt * 128);            \
      abl[BUF][mt] = *(const bf16x8*)(alc + mt * 128);            \
    }                                                             \
  } while (0)

#define PACK(BUF)                                                            \
  do {                                                                       \
    _Pragma("unroll") for (int f = 0; f < 4; ++f) {                          \
      union {                                                                \
        int i4[4];                                                           \
        bf16x8 v;                                                            \
      } u;                                                                   \
      _Pragma("unroll") for (int wd = 0; wd < 4; ++wd) {                     \
        unsigned lo = __float_as_uint((float)rw[BUF][2 * wd][f]);            \
        unsigned hi = __float_as_uint((float)rw[BUF][2 * wd + 1][f]);        \
        /* v_perm_b32: D = {hi[31:16], lo[31:16]} — exact bf16 pack */       \
        u.i4[wd] = (int)__builtin_amdgcn_perm(hi, lo, 0x07060302u);          \
      }                                                                      \
      bfr[f] = u.v;                                                          \
    }                                                                        \
  } while (0)

#define MMA(BUF)                                                             \
  do {                                                                       \
    _Pragma("unroll") for (int mt = 0; mt < 4; ++mt) {                       \
      _Pragma("unroll") for (int f = 0; f < 4; ++f) {                        \
        acc[mt][f] = __builtin_amdgcn_mfma_f32_16x16x32_bf16(                \
            abh[BUF][mt], bfr[f], acc[mt][f], 0, 0, 0);                      \
        acc[mt][f] = __builtin_amdgcn_mfma_f32_16x16x32_bf16(                \
            abl[BUF][mt], bfr[f], acc[mt][f], 0, 0, 0);                      \
      }                                                                      \
      acc1[mt] = __builtin_amdgcn_mfma_f32_16x16x32_bf16(                    \
          abh[BUF][mt], bones, acc1[mt], 0, 0, 0);                           \
      acc1[mt] = __builtin_amdgcn_mfma_f32_16x16x32_bf16(                    \
          abl[BUF][mt], bones, acc1[mt], 0, 0, 0);                           \
    }                                                                        \
  } while (0)

  LOADW(0, 0);
  LOADA(0, 0);
  LOADW(1, 1);
  LOADA(1, 1);
  for (int c = 0; c < WCHUNKS; c += 2) {  // literal buffer indices in body
    PACK(0);                    // waits on chunk c's W; frees rw[0]
    if (c + 2 < WCHUNKS) LOADW(c + 2, 0);  // W queue stays fed through MFMAs
    MMA(0);                     // consumes abh[0]/abl[0] + bfr
    if (c + 2 < WCHUNKS) LOADA(c + 2, 0);  // safe: A buf 0 now free
    PACK(1);
    if (c + 3 < WCHUNKS) LOADW(c + 3, 1);
    MMA(1);
    if (c + 3 < WCHUNKS) LOADA(c + 3, 1);
  }
#undef LOADW
#undef LOADA
#undef PACK
#undef MMA

  // two-stage intra-block k-reduction (conflict-free index):
  // storage col f*16+lnk holds actual col 4*lnk+f -> epilogue un-permutes.
  if (wv < 4) {
#pragma unroll
    for (int f = 0; f < 4; ++f)
#pragma unroll
      for (int mt = 0; mt < 4; ++mt)
#pragma unroll
        for (int r = 0; r < 4; ++r)
          red[wv][mt * 16 + quad * 4 + r][f * 16 + lnk] = acc[mt][f][r];
    if (lnk == 0) {
#pragma unroll
      for (int mt = 0; mt < 4; ++mt)
#pragma unroll
        for (int r = 0; r < 4; ++r)
          red[wv][mt * 16 + quad * 4 + r][64] = acc1[mt][r];
    }
  }
  __syncthreads();
  if (wv >= 4) {
#pragma unroll
    for (int f = 0; f < 4; ++f)
#pragma unroll
      for (int mt = 0; mt < 4; ++mt)
#pragma unroll
        for (int r = 0; r < 4; ++r)
          red[wv - 4][mt * 16 + quad * 4 + r][f * 16 + lnk] += acc[mt][f][r];
    if (lnk == 0) {
#pragma unroll
      for (int mt = 0; mt < 4; ++mt)
#pragma unroll
        for (int r = 0; r < 4; ++r)
          red[wv - 4][mt * 16 + quad * 4 + r][64] += acc1[mt][r];
    }
  }
  __syncthreads();

  // fused epilogue: out = scale*sum + scale*offset*rowsum[m] + bias
  // storage col nc <-> actual col 4*(nc&15) + (nc>>4)
#pragma unroll
  for (int i = 0; i < 8; ++i) {
    int idx = t + i * 512;
    int m = idx >> 6;
    int nc = idx & 63;
    float s = red[0][m][nc] + red[1][m][nc] + red[2][m][nc] + red[3][m][nc];
    float rs = red[0][m][64] + red[1][m][64] + red[2][m][64] + red[3][m][64];
    int n = nbase + 4 * (nc & 15) + (nc >> 4);
    float sc = scale[n];
    out[(size_t)m * N_DIM + n] = s * sc + sc * offset[n] * rs + bias[n];
  }
}

extern "C" void kernel_launch(void* const* d_in, const int* in_sizes, int n_in,
                              void* d_out, int out_size, void* d_ws,
                              size_t ws_size, hipStream_t stream) {
  const float* x = (const float*)d_in[0];
  const int* W = (const int*)d_in[1];
  const float* scale = (const float*)d_in[2];
  const float* offset = (const float*)d_in[3];
  const float* bias = (const float*)d_in[4];
  float* out = (float*)d_out;

  char* wsb = (char*)d_ws;
  u16* xh = (u16*)wsb;                          // 512 KB
  u16* xl = xh + (size_t)M_DIM * K_DIM;         // 512 KB

  prep_split<<<256, 128, 0, stream>>>(x, xh, xl);
  wqmm<<<NBLKS, 512, 0, stream>>>(W, xh, xl, scale, offset, bias, out);
}